// Round 3
// baseline (540.021 us; speedup 1.0000x reference)
//
#include <hip/hip_runtime.h>
#include <math.h>

// out[i, j, k] = K[j, k] * a[i, k],  K[j, m] = exp(-GAMMA * ||a_j - b_m||^2)
// N = 1024, M = D = 128. Softmax over a length-1 axis == 1, so
// rotation_params/entangle_params are mathematically dead.
// Write-bandwidth bound: 512 MiB output; floor ~85 us at 6.3 TB/s.

#define GAMMA_F 1.0f
#define N_ROWS 1024
#define DIM    128

// Native vector type — __builtin_nontemporal_store rejects HIP_vector_type.
typedef float f32x4 __attribute__((ext_vector_type(4)));

// ---------------------------------------------------------------------------
// Kernel 1: K[j, m] = exp(-||a_j - b_m||^2).  grid = 1024 blocks, 128 threads.
// a-row staged in LDS (float4), each thread streams its own b-row (L2-hot).
// ~2-3 us, negligible.
// ---------------------------------------------------------------------------
__global__ __launch_bounds__(DIM) void compute_K_kernel(
    const float* __restrict__ a,
    const float* __restrict__ b,
    float* __restrict__ K)
{
    __shared__ f32x4 a_sh[DIM / 4];
    const int j = blockIdx.x;
    const int m = threadIdx.x;

    if (m < DIM / 4) {
        a_sh[m] = reinterpret_cast<const f32x4*>(a + (size_t)j * DIM)[m];
    }
    __syncthreads();

    const f32x4* b4 = reinterpret_cast<const f32x4*>(b + (size_t)m * DIM);
    float acc = 0.0f;
#pragma unroll 8
    for (int d = 0; d < DIM / 4; ++d) {
        const f32x4 av = a_sh[d];
        const f32x4 bv = b4[d];
        const float dx = av.x - bv.x;
        const float dy = av.y - bv.y;
        const float dz = av.z - bv.z;
        const float dw = av.w - bv.w;
        acc = fmaf(dx, dx, acc);
        acc = fmaf(dy, dy, acc);
        acc = fmaf(dz, dz, acc);
        acc = fmaf(dw, dw, acc);
    }
    K[(size_t)j * DIM + m] = expf(-GAMMA_F * acc);
}

// ---------------------------------------------------------------------------
// Kernel 2: block b owns row i = b>>3 and j-tile [ (b&7)*128, +128 ).
// Thread t: k4 = t & 31 (float4 column), sub = t >> 5 (0..7).
// av cached in register once; 16 fully-unrolled independent
// load-K/mul/store chains per thread. Wave stores 1 KB contiguous per iter,
// block writes 64 KB contiguous total. 8192 blocks.
// ---------------------------------------------------------------------------
__global__ __launch_bounds__(256) void bcast_mul_kernel(
    const f32x4* __restrict__ a4,
    const f32x4* __restrict__ K4,
    f32x4* __restrict__ out4)
{
    const int i   = blockIdx.x >> 3;          // 0..1023
    const int j0  = (blockIdx.x & 7) << 7;    // 0,128,...,896
    const int k4  = threadIdx.x & 31;         // float4 column
    const int sub = threadIdx.x >> 5;         // 0..7

    const f32x4 av = a4[i * 32 + k4];

    const f32x4* __restrict__ Kp = K4 + (size_t)(j0 + sub) * 32 + k4;
    f32x4* __restrict__ Op = out4 + ((size_t)i * 1024 + j0 + sub) * 32 + k4;

#pragma unroll
    for (int jj = 0; jj < 16; ++jj) {
        const f32x4 kv = Kp[(size_t)jj * 8 * 32];
        f32x4 o = av * kv;
        __builtin_nontemporal_store(o, &Op[(size_t)jj * 8 * 32]);
    }
}

extern "C" void kernel_launch(void* const* d_in, const int* in_sizes, int n_in,
                              void* d_out, int out_size, void* d_ws, size_t ws_size,
                              hipStream_t stream)
{
    const float* a = reinterpret_cast<const float*>(d_in[0]);   // [1024, 128]
    const float* b = reinterpret_cast<const float*>(d_in[1]);   // [128, 128]
    // d_in[2], d_in[3] (rotation/entangle params) are dead: softmax over a
    // length-1 axis is identically 1, so attn_weights == a.

    float* K = reinterpret_cast<float*>(d_ws);                  // [1024, 128] scratch (512 KB)

    compute_K_kernel<<<N_ROWS, DIM, 0, stream>>>(a, b, K);

    bcast_mul_kernel<<<N_ROWS * 8, 256, 0, stream>>>(
        reinterpret_cast<const f32x4*>(a),
        reinterpret_cast<const f32x4*>(K),
        reinterpret_cast<f32x4*>(d_out));
}